// Round 1
// baseline (523.854 us; speedup 1.0000x reference)
//
#include <hip/hip_runtime.h>
#include <math.h>

#define D 131072      // 512*16*16
#define Q 512
#define BB 2
#define AA 16
#define CC 19
#define HW 65536      // 256*256
#define REFINE_CONF 0.968f

// ---------------- kernel 1: dist2[b][q] = ||queue[q] - tgt[b]||^2 ----------------
__global__ __launch_bounds__(256) void k_dist2(const float* __restrict__ queue,
                                               const float* __restrict__ tgt,
                                               float* __restrict__ dist2) {
    const int q = blockIdx.x;
    const int t = threadIdx.x;
    const float4* __restrict__ qr = (const float4*)(queue + (size_t)q * D);
    const float4* __restrict__ t0 = (const float4*)(tgt);
    const float4* __restrict__ t1 = (const float4*)(tgt + D);
    float a0 = 0.f, a1 = 0.f;
    for (int i = t; i < D / 4; i += 256) {
        float4 qv = qr[i];
        float4 u  = t0[i];
        float4 v  = t1[i];
        float d;
        d = qv.x - u.x; a0 = fmaf(d, d, a0);
        d = qv.y - u.y; a0 = fmaf(d, d, a0);
        d = qv.z - u.z; a0 = fmaf(d, d, a0);
        d = qv.w - u.w; a0 = fmaf(d, d, a0);
        d = qv.x - v.x; a1 = fmaf(d, d, a1);
        d = qv.y - v.y; a1 = fmaf(d, d, a1);
        d = qv.z - v.z; a1 = fmaf(d, d, a1);
        d = qv.w - v.w; a1 = fmaf(d, d, a1);
    }
    for (int o = 32; o > 0; o >>= 1) { a0 += __shfl_down(a0, o); a1 += __shfl_down(a1, o); }
    __shared__ float s0[4], s1[4];
    int lane = t & 63, wid = t >> 6;
    if (lane == 0) { s0[wid] = a0; s1[wid] = a1; }
    __syncthreads();
    if (t == 0) {
        dist2[q]     = s0[0] + s0[1] + s0[2] + s0[3];
        dist2[Q + q] = s1[0] + s1[1] + s1[2] + s1[3];
    }
}

// ---------------- kernel 2: argmin over q (first-index ties, like np) ----------------
__global__ __launch_bounds__(512) void k_argmin(const float* __restrict__ dist2,
                                                int* __restrict__ imin,
                                                float* __restrict__ minval) {
    const int b = blockIdx.x;
    const int t = threadIdx.x;   // 512 threads
    __shared__ float sv[512];
    __shared__ int   si[512];
    sv[t] = dist2[b * Q + t];
    si[t] = t;
    __syncthreads();
    for (int s = 256; s > 0; s >>= 1) {
        if (t < s) {
            float v2 = sv[t + s]; int i2 = si[t + s];
            if (v2 < sv[t] || (v2 == sv[t] && i2 < si[t])) { sv[t] = v2; si[t] = i2; }
        }
        __syncthreads();
    }
    if (t == 0) { imin[b] = si[0]; minval[b] = sv[0]; }
}

// ---------------- kernel 3: d2sq[b][a] = ||auged[b][a] - queue[imin[b]]||^2 ----------------
__global__ __launch_bounds__(256) void k_d2(const float* __restrict__ queue,
                                            const float* __restrict__ auged,
                                            const int* __restrict__ imin,
                                            float* __restrict__ d2sq) {
    const int ba = blockIdx.x;           // b*16 + a
    const int b  = ba >> 4;
    const int t  = threadIdx.x;
    const float4* __restrict__ cr = (const float4*)(queue + (size_t)imin[b] * D);
    const float4* __restrict__ ar = (const float4*)(auged + (size_t)ba * D);
    float acc = 0.f;
    for (int i = t; i < D / 4; i += 256) {
        float4 c4 = cr[i];
        float4 a4 = ar[i];
        float d;
        d = a4.x - c4.x; acc = fmaf(d, d, acc);
        d = a4.y - c4.y; acc = fmaf(d, d, acc);
        d = a4.z - c4.z; acc = fmaf(d, d, acc);
        d = a4.w - c4.w; acc = fmaf(d, d, acc);
    }
    for (int o = 32; o > 0; o >>= 1) acc += __shfl_down(acc, o);
    __shared__ float s0[4];
    int lane = t & 63, wid = t >> 6;
    if (lane == 0) s0[wid] = acc;
    __syncthreads();
    if (t == 0) d2sq[ba] = s0[0] + s0[1] + s0[2] + s0[3];
}

// ---------------- kernel 4: mask + top-k selection (tiny, 1 thread per b) ----------------
__global__ __launch_bounds__(64) void k_select(const float* __restrict__ d2sq,
                                               const float* __restrict__ minval,
                                               const int* __restrict__ kptr,
                                               int* __restrict__ selidx,
                                               float* __restrict__ wsel,
                                               float* __restrict__ wsumdiv,
                                               int* __restrict__ countspos) {
    const int b = threadIdx.x;
    if (b >= BB) return;
    int k = *kptr;
    if (k > AA) k = AA;
    if (k < 0) k = 0;
    const float cd = sqrtf(minval[b]);
    float vals[AA];
    int cnt = 0;
    for (int a = 0; a < AA; ++a) {
        float dd = sqrtf(d2sq[b * AA + a]);
        bool m = (dd <= cd);
        if (m) cnt++;
        vals[a] = m ? dd : INFINITY;
    }
    float ws = 0.f;
    for (int kk = 0; kk < k; ++kk) {
        int bi = 0; float bv = vals[0];
        for (int a = 1; a < AA; ++a)
            if (vals[a] < bv) { bv = vals[a]; bi = a; }   // strict < => lowest index on ties
        selidx[b * AA + kk] = bi;
        float w = isinf(bv) ? 0.f : 1.f;
        wsel[b * AA + kk] = w;
        ws += w;
        vals[bi] = INFINITY;
    }
    // pad remaining slots (defensive init; never read past k)
    for (int kk = k; kk < AA; ++kk) { selidx[b * AA + kk] = 0; wsel[b * AA + kk] = 0.f; }
    wsumdiv[b]   = fmaxf(ws, 1.f);
    countspos[b] = (cnt > 0) ? 1 : 0;
}

// ---------------- kernel 5: fused softmax-avg / argmax / refinement ----------------
__global__ __launch_bounds__(256) void k_refine(const float* __restrict__ auged_logits,
                                                const float* __restrict__ tgt_logits,
                                                const int*   __restrict__ pseudo,
                                                const int*   __restrict__ selidx,
                                                const float* __restrict__ wsel,
                                                const float* __restrict__ wsumdiv,
                                                const int*   __restrict__ countspos,
                                                const int*   __restrict__ kptr,
                                                float* __restrict__ out_refined,
                                                float* __restrict__ out_avg) {
    const int p = blockIdx.x * 256 + threadIdx.x;    // global pixel in [0, B*HW)
    const int b   = p >> 16;                          // HW = 65536, whole blocks share b
    const int pix = p & (HW - 1);

    __shared__ int   s_idx[AA];
    __shared__ float s_w[AA];
    __shared__ float s_wd;
    __shared__ int   s_cp;
    __shared__ int   s_k;
    if (threadIdx.x == 0) {
        s_wd = wsumdiv[b];
        s_cp = countspos[b];
        int k = *kptr; if (k > AA) k = AA; if (k < 0) k = 0;
        s_k = k;
    }
    if (threadIdx.x < AA) {
        s_idx[threadIdx.x] = selidx[b * AA + threadIdx.x];
        s_w[threadIdx.x]   = wsel[b * AA + threadIdx.x];
    }
    __syncthreads();

    float acc[CC];
#pragma unroll
    for (int c = 0; c < CC; ++c) acc[c] = 0.f;

    const int k = s_k;
    for (int kk = 0; kk < k; ++kk) {
        if (s_w[kk] == 0.f) break;   // weights are sorted: finite first (wave-uniform branch)
        const int a = s_idx[kk];
        const float* base = auged_logits + ((size_t)(b * AA + a) * CC) * HW + pix;
        float l[CC];
        float m = -INFINITY;
#pragma unroll
        for (int c = 0; c < CC; ++c) { l[c] = base[(size_t)c * HW]; m = fmaxf(m, l[c]); }
        float se = 0.f;
#pragma unroll
        for (int c = 0; c < CC; ++c) { l[c] = expf(l[c] - m); se += l[c]; }
#pragma unroll
        for (int c = 0; c < CC; ++c) acc[c] += l[c] / se;
    }

    const float wd = s_wd;
    int best = 0; float bv = -INFINITY;
#pragma unroll
    for (int c = 0; c < CC; ++c) {
        float av = acc[c] / wd;
        out_avg[((size_t)(b * CC + c)) * HW + pix] = av;
        if (av > bv) { bv = av; best = c; }   // strict > => first index on ties (np argmax)
    }

    // target confidence gate: max softmax prob = 1 / sum(exp(l - max))
    const float* tb = tgt_logits + (size_t)b * CC * HW + pix;
    float tl[CC];
    float tm = -INFINITY;
#pragma unroll
    for (int c = 0; c < CC; ++c) { tl[c] = tb[(size_t)c * HW]; tm = fmaxf(tm, tl[c]); }
    float tse = 0.f;
#pragma unroll
    for (int c = 0; c < CC; ++c) tse += expf(tl[c] - tm);
    const float pmax = 1.f / tse;

    const int pl      = pseudo[p];
    const int label   = s_cp ? best : pl;
    const int refined = (pmax < REFINE_CONF) ? label : pl;
    out_refined[p] = (float)refined;
}

extern "C" void kernel_launch(void* const* d_in, const int* in_sizes, int n_in,
                              void* d_out, int out_size, void* d_ws, size_t ws_size,
                              hipStream_t stream) {
    const float* queue        = (const float*)d_in[0];   // [512,512,16,16]
    const float* tgt          = (const float*)d_in[1];   // [2,512,16,16]
    const float* tgt_logits   = (const float*)d_in[2];   // [2,19,256,256]
    const float* auged_feat   = (const float*)d_in[3];   // [2,16,512,16,16]
    const float* auged_logits = (const float*)d_in[4];   // [2,16,19,256,256]
    const int*   pseudo       = (const int*)d_in[5];     // [2,256,256]
    const int*   kptr         = (const int*)d_in[6];     // scalar k

    float* ws        = (float*)d_ws;                     // needs ~4.6 KB
    float* dist2     = ws;                               // [2*512]
    float* d2sq      = ws + 1024;                        // [2*16]
    float* minval    = ws + 1056;                        // [2]
    int*   imin      = (int*)(ws + 1058);                // [2]
    int*   selidx    = (int*)(ws + 1060);                // [2*16]
    float* wsel      = ws + 1092;                        // [2*16]
    float* wsumdiv   = ws + 1124;                        // [2]
    int*   countspos = (int*)(ws + 1126);                // [2]

    float* out_refined = (float*)d_out;                  // [2*256*256] labels as float
    float* out_avg     = (float*)d_out + BB * HW;        // [2*19*256*256]

    hipLaunchKernelGGL(k_dist2,  dim3(Q),        dim3(256), 0, stream, queue, tgt, dist2);
    hipLaunchKernelGGL(k_argmin, dim3(BB),       dim3(512), 0, stream, dist2, imin, minval);
    hipLaunchKernelGGL(k_d2,     dim3(BB * AA),  dim3(256), 0, stream, queue, auged_feat, imin, d2sq);
    hipLaunchKernelGGL(k_select, dim3(1),        dim3(64),  0, stream, d2sq, minval, kptr,
                       selidx, wsel, wsumdiv, countspos);
    hipLaunchKernelGGL(k_refine, dim3((BB * HW) / 256), dim3(256), 0, stream,
                       auged_logits, tgt_logits, pseudo, selidx, wsel, wsumdiv, countspos, kptr,
                       out_refined, out_avg);
}

// Round 2
// 462.702 us; speedup vs baseline: 1.1322x; 1.1322x over previous
//
#include <hip/hip_runtime.h>
#include <math.h>

#define D 131072      // 512*16*16
#define Q 512
#define BB 2
#define AA 16
#define CC 19
#define HW 65536      // 256*256
#define REFINE_CONF 0.968f

#define CH1 4         // chunks per queue row in k_dist2  (D/CH1 = 32768 floats)
#define CH2 8         // chunks per row in k_d2           (D/CH2 = 16384 floats)

// ---------------- kernel 1: partial dist2: part[b][q][ch] ----------------
// grid (Q, CH1), 256 threads. Each block: 32 float4/thread.
__global__ __launch_bounds__(256) void k_dist2(const float* __restrict__ queue,
                                               const float* __restrict__ tgt,
                                               float* __restrict__ part) {
    const int q  = blockIdx.x;
    const int ch = blockIdx.y;
    const int t  = threadIdx.x;
    const int off4 = ch * (D / CH1 / 4);                 // float4 offset of this chunk
    const float4* __restrict__ qr = (const float4*)(queue + (size_t)q * D) + off4;
    const float4* __restrict__ t0 = (const float4*)(tgt) + off4;
    const float4* __restrict__ t1 = (const float4*)(tgt + D) + off4;
    float a0 = 0.f, a1 = 0.f;
#pragma unroll 4
    for (int i = t; i < D / CH1 / 4; i += 256) {
        float4 qv = qr[i];
        float4 u  = t0[i];
        float4 v  = t1[i];
        float d;
        d = qv.x - u.x; a0 = fmaf(d, d, a0);
        d = qv.y - u.y; a0 = fmaf(d, d, a0);
        d = qv.z - u.z; a0 = fmaf(d, d, a0);
        d = qv.w - u.w; a0 = fmaf(d, d, a0);
        d = qv.x - v.x; a1 = fmaf(d, d, a1);
        d = qv.y - v.y; a1 = fmaf(d, d, a1);
        d = qv.z - v.z; a1 = fmaf(d, d, a1);
        d = qv.w - v.w; a1 = fmaf(d, d, a1);
    }
    for (int o = 32; o > 0; o >>= 1) { a0 += __shfl_down(a0, o); a1 += __shfl_down(a1, o); }
    __shared__ float s0[4], s1[4];
    int lane = t & 63, wid = t >> 6;
    if (lane == 0) { s0[wid] = a0; s1[wid] = a1; }
    __syncthreads();
    if (t == 0) {
        part[(size_t)q * CH1 + ch]            = s0[0] + s0[1] + s0[2] + s0[3];
        part[(size_t)(Q + q) * CH1 + ch]      = s1[0] + s1[1] + s1[2] + s1[3];
    }
}

// ---------------- kernel 2: fold partials + argmin (first-index ties) ----------------
__global__ __launch_bounds__(512) void k_argmin(const float* __restrict__ part,
                                                int* __restrict__ imin,
                                                float* __restrict__ minval) {
    const int b = blockIdx.x;
    const int t = threadIdx.x;   // 512 threads, one per q
    __shared__ float sv[512];
    __shared__ int   si[512];
    const float* p = part + (size_t)(b * Q + t) * CH1;
    sv[t] = p[0] + p[1] + p[2] + p[3];
    si[t] = t;
    __syncthreads();
    for (int s = 256; s > 0; s >>= 1) {
        if (t < s) {
            float v2 = sv[t + s]; int i2 = si[t + s];
            if (v2 < sv[t] || (v2 == sv[t] && i2 < si[t])) { sv[t] = v2; si[t] = i2; }
        }
        __syncthreads();
    }
    if (t == 0) { imin[b] = si[0]; minval[b] = sv[0]; }
}

// ---------------- kernel 3: partial d2: part2[ba][ch] ----------------
// grid (BB*AA, CH2), 256 threads. 16 float4/thread.
__global__ __launch_bounds__(256) void k_d2(const float* __restrict__ queue,
                                            const float* __restrict__ auged,
                                            const int* __restrict__ imin,
                                            float* __restrict__ part2) {
    const int ba = blockIdx.x;           // b*16 + a
    const int ch = blockIdx.y;
    const int b  = ba >> 4;
    const int t  = threadIdx.x;
    const int off4 = ch * (D / CH2 / 4);
    const float4* __restrict__ cr = (const float4*)(queue + (size_t)imin[b] * D) + off4;
    const float4* __restrict__ ar = (const float4*)(auged + (size_t)ba * D) + off4;
    float acc = 0.f;
#pragma unroll 4
    for (int i = t; i < D / CH2 / 4; i += 256) {
        float4 c4 = cr[i];
        float4 a4 = ar[i];
        float d;
        d = a4.x - c4.x; acc = fmaf(d, d, acc);
        d = a4.y - c4.y; acc = fmaf(d, d, acc);
        d = a4.z - c4.z; acc = fmaf(d, d, acc);
        d = a4.w - c4.w; acc = fmaf(d, d, acc);
    }
    for (int o = 32; o > 0; o >>= 1) acc += __shfl_down(acc, o);
    __shared__ float s0[4];
    int lane = t & 63, wid = t >> 6;
    if (lane == 0) s0[wid] = acc;
    __syncthreads();
    if (t == 0) part2[(size_t)ba * CH2 + ch] = s0[0] + s0[1] + s0[2] + s0[3];
}

// ---------------- kernel 4: fold partials + mask + top-k ----------------
__global__ __launch_bounds__(64) void k_select(const float* __restrict__ part2,
                                               const float* __restrict__ minval,
                                               const int* __restrict__ kptr,
                                               int* __restrict__ selidx,
                                               float* __restrict__ wsel,
                                               float* __restrict__ wsumdiv,
                                               int* __restrict__ countspos) {
    __shared__ float s_d2[BB * AA];
    const int t = threadIdx.x;
    if (t < BB * AA) {
        const float* p = part2 + (size_t)t * CH2;
        float s = 0.f;
#pragma unroll
        for (int c = 0; c < CH2; ++c) s += p[c];
        s_d2[t] = s;
    }
    __syncthreads();
    const int b = t;
    if (b >= BB) return;
    int k = *kptr;
    if (k > AA) k = AA;
    if (k < 0) k = 0;
    const float cd = sqrtf(minval[b]);
    float vals[AA];
    int cnt = 0;
    for (int a = 0; a < AA; ++a) {
        float dd = sqrtf(s_d2[b * AA + a]);
        bool m = (dd <= cd);
        if (m) cnt++;
        vals[a] = m ? dd : INFINITY;
    }
    float ws = 0.f;
    for (int kk = 0; kk < k; ++kk) {
        int bi = 0; float bv = vals[0];
        for (int a = 1; a < AA; ++a)
            if (vals[a] < bv) { bv = vals[a]; bi = a; }   // strict < => lowest index on ties
        selidx[b * AA + kk] = bi;
        float w = isinf(bv) ? 0.f : 1.f;
        wsel[b * AA + kk] = w;
        ws += w;
        vals[bi] = INFINITY;
    }
    for (int kk = k; kk < AA; ++kk) { selidx[b * AA + kk] = 0; wsel[b * AA + kk] = 0.f; }
    wsumdiv[b]   = fmaxf(ws, 1.f);
    countspos[b] = (cnt > 0) ? 1 : 0;
}

// ---------------- kernel 5: fused softmax-avg / argmax / refinement ----------------
__global__ __launch_bounds__(256) void k_refine(const float* __restrict__ auged_logits,
                                                const float* __restrict__ tgt_logits,
                                                const int*   __restrict__ pseudo,
                                                const int*   __restrict__ selidx,
                                                const float* __restrict__ wsel,
                                                const float* __restrict__ wsumdiv,
                                                const int*   __restrict__ countspos,
                                                const int*   __restrict__ kptr,
                                                float* __restrict__ out_refined,
                                                float* __restrict__ out_avg) {
    const int p = blockIdx.x * 256 + threadIdx.x;    // global pixel in [0, B*HW)
    const int b   = p >> 16;                          // HW = 65536, whole blocks share b
    const int pix = p & (HW - 1);

    __shared__ int   s_idx[AA];
    __shared__ float s_w[AA];
    __shared__ float s_wd;
    __shared__ int   s_cp;
    __shared__ int   s_k;
    if (threadIdx.x == 0) {
        s_wd = wsumdiv[b];
        s_cp = countspos[b];
        int k = *kptr; if (k > AA) k = AA; if (k < 0) k = 0;
        s_k = k;
    }
    if (threadIdx.x < AA) {
        s_idx[threadIdx.x] = selidx[b * AA + threadIdx.x];
        s_w[threadIdx.x]   = wsel[b * AA + threadIdx.x];
    }
    __syncthreads();

    float acc[CC];
#pragma unroll
    for (int c = 0; c < CC; ++c) acc[c] = 0.f;

    const int k = s_k;
    for (int kk = 0; kk < k; ++kk) {
        if (s_w[kk] == 0.f) break;   // finite-first ordering; wave-uniform branch
        const int a = s_idx[kk];
        const float* base = auged_logits + ((size_t)(b * AA + a) * CC) * HW + pix;
        float l[CC];
        float m = -INFINITY;
#pragma unroll
        for (int c = 0; c < CC; ++c) { l[c] = base[(size_t)c * HW]; m = fmaxf(m, l[c]); }
        float se = 0.f;
#pragma unroll
        for (int c = 0; c < CC; ++c) { l[c] = expf(l[c] - m); se += l[c]; }
        float rse = 1.f / se;
#pragma unroll
        for (int c = 0; c < CC; ++c) acc[c] = fmaf(l[c], rse, acc[c]);
    }

    const float wd = s_wd;
    int best = 0; float bv = -INFINITY;
#pragma unroll
    for (int c = 0; c < CC; ++c) {
        float av = acc[c] / wd;
        out_avg[((size_t)(b * CC + c)) * HW + pix] = av;
        if (av > bv) { bv = av; best = c; }   // strict > => first index on ties (np argmax)
    }

    const float* tb = tgt_logits + (size_t)b * CC * HW + pix;
    float tl[CC];
    float tm = -INFINITY;
#pragma unroll
    for (int c = 0; c < CC; ++c) { tl[c] = tb[(size_t)c * HW]; tm = fmaxf(tm, tl[c]); }
    float tse = 0.f;
#pragma unroll
    for (int c = 0; c < CC; ++c) tse += expf(tl[c] - tm);
    const float pmax = 1.f / tse;

    const int pl      = pseudo[p];
    const int label   = s_cp ? best : pl;
    const int refined = (pmax < REFINE_CONF) ? label : pl;
    out_refined[p] = (float)refined;
}

extern "C" void kernel_launch(void* const* d_in, const int* in_sizes, int n_in,
                              void* d_out, int out_size, void* d_ws, size_t ws_size,
                              hipStream_t stream) {
    const float* queue        = (const float*)d_in[0];   // [512,512,16,16]
    const float* tgt          = (const float*)d_in[1];   // [2,512,16,16]
    const float* tgt_logits   = (const float*)d_in[2];   // [2,19,256,256]
    const float* auged_feat   = (const float*)d_in[3];   // [2,16,512,16,16]
    const float* auged_logits = (const float*)d_in[4];   // [2,16,19,256,256]
    const int*   pseudo       = (const int*)d_in[5];     // [2,256,256]
    const int*   kptr         = (const int*)d_in[6];     // scalar k

    float* ws        = (float*)d_ws;
    float* part      = ws;                               // [2*512*CH1] = 4096
    float* part2     = ws + 4096;                        // [32*CH2]   = 256
    float* minval    = ws + 4352;                        // [2]
    int*   imin      = (int*)(ws + 4354);                // [2]
    int*   selidx    = (int*)(ws + 4356);                // [2*16]
    float* wsel      = ws + 4388;                        // [2*16]
    float* wsumdiv   = ws + 4420;                        // [2]
    int*   countspos = (int*)(ws + 4422);                // [2]

    float* out_refined = (float*)d_out;                  // [2*256*256]
    float* out_avg     = (float*)d_out + BB * HW;        // [2*19*256*256]

    hipLaunchKernelGGL(k_dist2,  dim3(Q, CH1),       dim3(256), 0, stream, queue, tgt, part);
    hipLaunchKernelGGL(k_argmin, dim3(BB),           dim3(512), 0, stream, part, imin, minval);
    hipLaunchKernelGGL(k_d2,     dim3(BB * AA, CH2), dim3(256), 0, stream, queue, auged_feat, imin, part2);
    hipLaunchKernelGGL(k_select, dim3(1),            dim3(64),  0, stream, part2, minval, kptr,
                       selidx, wsel, wsumdiv, countspos);
    hipLaunchKernelGGL(k_refine, dim3((BB * HW) / 256), dim3(256), 0, stream,
                       auged_logits, tgt_logits, pseudo, selidx, wsel, wsumdiv, countspos, kptr,
                       out_refined, out_avg);
}

// Round 3
// 461.620 us; speedup vs baseline: 1.1348x; 1.0023x over previous
//
#include <hip/hip_runtime.h>
#include <math.h>

#define D 131072      // 512*16*16
#define Q 512
#define BB 2
#define AA 16
#define CC 19
#define HW 65536      // 256*256
#define REFINE_CONF 0.968f

#define CH1 4         // chunks per queue row in k_dist2  (D/CH1 = 32768 floats)
#define CH2 8         // chunks per row in k_d2           (D/CH2 = 16384 floats)

// ---------------- kernel 1: partial dist2: part[b][q][ch] ----------------
// grid (Q, CH1), 256 threads. 32 float4/thread.
__global__ __launch_bounds__(256) void k_dist2(const float* __restrict__ queue,
                                               const float* __restrict__ tgt,
                                               float* __restrict__ part) {
    const int q  = blockIdx.x;
    const int ch = blockIdx.y;
    const int t  = threadIdx.x;
    const int off4 = ch * (D / CH1 / 4);
    const float4* __restrict__ qr = (const float4*)(queue + (size_t)q * D) + off4;
    const float4* __restrict__ t0 = (const float4*)(tgt) + off4;
    const float4* __restrict__ t1 = (const float4*)(tgt + D) + off4;
    float a0 = 0.f, a1 = 0.f;
#pragma unroll 4
    for (int i = t; i < D / CH1 / 4; i += 256) {
        float4 qv = qr[i];
        float4 u  = t0[i];
        float4 v  = t1[i];
        float d;
        d = qv.x - u.x; a0 = fmaf(d, d, a0);
        d = qv.y - u.y; a0 = fmaf(d, d, a0);
        d = qv.z - u.z; a0 = fmaf(d, d, a0);
        d = qv.w - u.w; a0 = fmaf(d, d, a0);
        d = qv.x - v.x; a1 = fmaf(d, d, a1);
        d = qv.y - v.y; a1 = fmaf(d, d, a1);
        d = qv.z - v.z; a1 = fmaf(d, d, a1);
        d = qv.w - v.w; a1 = fmaf(d, d, a1);
    }
    for (int o = 32; o > 0; o >>= 1) { a0 += __shfl_down(a0, o); a1 += __shfl_down(a1, o); }
    __shared__ float s0[4], s1[4];
    int lane = t & 63, wid = t >> 6;
    if (lane == 0) { s0[wid] = a0; s1[wid] = a1; }
    __syncthreads();
    if (t == 0) {
        part[(size_t)q * CH1 + ch]       = s0[0] + s0[1] + s0[2] + s0[3];
        part[(size_t)(Q + q) * CH1 + ch] = s1[0] + s1[1] + s1[2] + s1[3];
    }
}

// Device helper: fold part[] for batch b and return (minval, imin) via LDS.
// 256 threads; sv/si are caller-provided LDS (size 256 each).
__device__ __forceinline__ void fold_argmin(const float* __restrict__ part, int b, int t,
                                            float* sv, int* si) {
    const float* p0 = part + (size_t)(b * Q + t) * CH1;
    const float* p1 = part + (size_t)(b * Q + t + 256) * CH1;
    float v0 = p0[0] + p0[1] + p0[2] + p0[3];
    float v1 = p1[0] + p1[1] + p1[2] + p1[3];
    if (v1 < v0) { sv[t] = v1; si[t] = t + 256; }       // strict < => lower index on ties
    else         { sv[t] = v0; si[t] = t; }
    __syncthreads();
    for (int s = 128; s > 0; s >>= 1) {
        if (t < s) {
            float v2 = sv[t + s]; int i2 = si[t + s];
            if (v2 < sv[t] || (v2 == sv[t] && i2 < si[t])) { sv[t] = v2; si[t] = i2; }
        }
        __syncthreads();
    }
}

// ---------------- kernel 2: argmin (redundant per block) + partial d2 ----------------
// grid (BB*AA, CH2), 256 threads.
__global__ __launch_bounds__(256) void k_d2(const float* __restrict__ queue,
                                            const float* __restrict__ auged,
                                            const float* __restrict__ part,
                                            float* __restrict__ part2) {
    const int ba = blockIdx.x;           // b*16 + a
    const int ch = blockIdx.y;
    const int b  = ba >> 4;
    const int t  = threadIdx.x;
    __shared__ float sv[256];
    __shared__ int   si[256];
    fold_argmin(part, b, t, sv, si);
    const int im = si[0];

    const int off4 = ch * (D / CH2 / 4);
    const float4* __restrict__ cr = (const float4*)(queue + (size_t)im * D) + off4;
    const float4* __restrict__ ar = (const float4*)(auged + (size_t)ba * D) + off4;
    float acc = 0.f;
#pragma unroll 4
    for (int i = t; i < D / CH2 / 4; i += 256) {
        float4 c4 = cr[i];
        float4 a4 = ar[i];
        float d;
        d = a4.x - c4.x; acc = fmaf(d, d, acc);
        d = a4.y - c4.y; acc = fmaf(d, d, acc);
        d = a4.z - c4.z; acc = fmaf(d, d, acc);
        d = a4.w - c4.w; acc = fmaf(d, d, acc);
    }
    for (int o = 32; o > 0; o >>= 1) acc += __shfl_down(acc, o);
    __shared__ float s0[4];
    int lane = t & 63, wid = t >> 6;
    if (lane == 0) s0[wid] = acc;
    __syncthreads();
    if (t == 0) part2[(size_t)ba * CH2 + ch] = s0[0] + s0[1] + s0[2] + s0[3];
}

// ---------------- kernel 3: selection (redundant per block) + fused epilogue ----------------
// grid (BB*HW/256), 256 threads, 1 pixel/thread.
__global__ __launch_bounds__(256) void k_refine(const float* __restrict__ auged_logits,
                                                const float* __restrict__ tgt_logits,
                                                const int*   __restrict__ pseudo,
                                                const float* __restrict__ part,
                                                const float* __restrict__ part2,
                                                const int*   __restrict__ kptr,
                                                float* __restrict__ out_refined,
                                                float* __restrict__ out_avg) {
    const int p   = blockIdx.x * 256 + threadIdx.x;
    const int b   = p >> 16;                          // HW = 65536; whole block shares b
    const int pix = p & (HW - 1);
    const int t   = threadIdx.x;

    // ---- stage A: re-derive minval for this b (same fold/compare as k_d2) ----
    __shared__ float sv[256];
    __shared__ int   si[256];
    fold_argmin(part, b, t, sv, si);
    __shared__ float s_d2[AA];
    if (t < AA) {
        const float* pp = part2 + (size_t)(b * AA + t) * CH2;
        float s = 0.f;
#pragma unroll
        for (int c = 0; c < CH2; ++c) s += pp[c];
        s_d2[t] = s;
    }
    __syncthreads();

    // ---- stage B: thread 0 does mask + top-k selection ----
    __shared__ int   s_idx[AA];
    __shared__ int   s_kv;     // # selected finite (all have weight 1)
    __shared__ int   s_cp;     // counts > 0
    __shared__ float s_wd;     // max(sum w, 1)
    if (t == 0) {
        int k = *kptr; if (k > AA) k = AA; if (k < 0) k = 0;
        const float cd = sqrtf(sv[0]);
        float vals[AA];
        int cnt = 0;
        for (int a = 0; a < AA; ++a) {
            float dd = sqrtf(s_d2[a]);
            bool m = (dd <= cd);
            if (m) cnt++;
            vals[a] = m ? dd : INFINITY;
        }
        int kv = 0;
        for (int kk = 0; kk < k; ++kk) {
            int bi = 0; float bv = vals[0];
            for (int a = 1; a < AA; ++a)
                if (vals[a] < bv) { bv = vals[a]; bi = a; }   // strict < => first index on ties
            s_idx[kk] = bi;
            if (!isinf(bv)) kv++;
            vals[bi] = INFINITY;
        }
        s_kv = kv;
        s_wd = fmaxf((float)kv, 1.f);
        s_cp = (cnt > 0) ? 1 : 0;
    }
    __syncthreads();

    // ---- stage C: per-pixel fused softmax-avg / argmax / gate ----
    const int kv = s_kv;                               // grid-uniform
    const int pl = pseudo[p];

    // hoist tgt-logit loads so they overlap the aug loop
    const float* tb = tgt_logits + (size_t)b * CC * HW + pix;
    float tl[CC];
#pragma unroll
    for (int c = 0; c < CC; ++c) tl[c] = tb[(size_t)c * HW];

    float acc[CC];
#pragma unroll
    for (int c = 0; c < CC; ++c) acc[c] = 0.f;

    float lc[CC];
    if (kv > 0) {
        const float* base = auged_logits + ((size_t)(b * AA + s_idx[0]) * CC) * HW + pix;
#pragma unroll
        for (int c = 0; c < CC; ++c) lc[c] = base[(size_t)c * HW];
    }
    for (int kk = 0; kk < kv; ++kk) {
        float ln[CC];
        const bool more = (kk + 1 < kv);               // grid-uniform
        if (more) {
            const float* base = auged_logits + ((size_t)(b * AA + s_idx[kk + 1]) * CC) * HW + pix;
#pragma unroll
            for (int c = 0; c < CC; ++c) ln[c] = base[(size_t)c * HW];
        }
        float m = -INFINITY;
#pragma unroll
        for (int c = 0; c < CC; ++c) m = fmaxf(m, lc[c]);
        float se = 0.f;
#pragma unroll
        for (int c = 0; c < CC; ++c) { lc[c] = expf(lc[c] - m); se += lc[c]; }
        float rse = 1.f / se;
#pragma unroll
        for (int c = 0; c < CC; ++c) acc[c] = fmaf(lc[c], rse, acc[c]);
        if (more) {
#pragma unroll
            for (int c = 0; c < CC; ++c) lc[c] = ln[c];
        }
    }

    const float wd = s_wd;
    int best = 0; float bv = -INFINITY;
#pragma unroll
    for (int c = 0; c < CC; ++c) {
        float av = acc[c] / wd;
        out_avg[((size_t)(b * CC + c)) * HW + pix] = av;
        if (av > bv) { bv = av; best = c; }            // strict > => first index on ties
    }

    float tm = -INFINITY;
#pragma unroll
    for (int c = 0; c < CC; ++c) tm = fmaxf(tm, tl[c]);
    float tse = 0.f;
#pragma unroll
    for (int c = 0; c < CC; ++c) tse += expf(tl[c] - tm);
    const float pmax = 1.f / tse;

    const int label   = s_cp ? best : pl;
    const int refined = (pmax < REFINE_CONF) ? label : pl;
    out_refined[p] = (float)refined;
}

extern "C" void kernel_launch(void* const* d_in, const int* in_sizes, int n_in,
                              void* d_out, int out_size, void* d_ws, size_t ws_size,
                              hipStream_t stream) {
    const float* queue        = (const float*)d_in[0];   // [512,512,16,16]
    const float* tgt          = (const float*)d_in[1];   // [2,512,16,16]
    const float* tgt_logits   = (const float*)d_in[2];   // [2,19,256,256]
    const float* auged_feat   = (const float*)d_in[3];   // [2,16,512,16,16]
    const float* auged_logits = (const float*)d_in[4];   // [2,16,19,256,256]
    const int*   pseudo       = (const int*)d_in[5];     // [2,256,256]
    const int*   kptr         = (const int*)d_in[6];     // scalar k

    float* ws    = (float*)d_ws;
    float* part  = ws;                                   // [2*512*CH1] = 4096 floats
    float* part2 = ws + 4096;                            // [32*CH2]    = 256 floats

    float* out_refined = (float*)d_out;                  // [2*256*256]
    float* out_avg     = (float*)d_out + BB * HW;        // [2*19*256*256]

    hipLaunchKernelGGL(k_dist2, dim3(Q, CH1),       dim3(256), 0, stream, queue, tgt, part);
    hipLaunchKernelGGL(k_d2,    dim3(BB * AA, CH2), dim3(256), 0, stream, queue, auged_feat, part, part2);
    hipLaunchKernelGGL(k_refine, dim3((BB * HW) / 256), dim3(256), 0, stream,
                       auged_logits, tgt_logits, pseudo, part, part2, kptr,
                       out_refined, out_avg);
}